// Round 9
// baseline (512.059 us; speedup 1.0000x reference)
//
#include <hip/hip_runtime.h>

#define N_EXPERTS 48
#define D_IN 163840
#define D_OUT 2
#define BATCH 512
#define CHUNK_E 4096                    // elements of D_IN per block
#define NCHUNK (D_IN / CHUNK_E)         // 40
#define THREADS 256
#define F4T (CHUNK_E / 4 / THREADS)     // 4 float4 of x per thread

// clang-native float4 so __builtin_nontemporal_load accepts the pointer
typedef float nfloat4 __attribute__((ext_vector_type(4)));

// ---------------------------------------------------------------------------
// Pass 0: bucket-sort samples by expert + emit segment offsets, ONE block.
// ws ints: [0..511]   = sample ids in expert-sorted order
//          [512..560] = segment offsets per expert (off[48] = 512)
// ---------------------------------------------------------------------------
__global__ __launch_bounds__(BATCH) void bucket_kernel(const int* __restrict__ t,
                                                       int* __restrict__ ws) {
    __shared__ int cnt[N_EXPERTS];
    __shared__ int off[N_EXPERTS + 1];
    const int s = threadIdx.x;            // one thread per sample
    if (s < N_EXPERTS) cnt[s] = 0;
    __syncthreads();
    const int e = (t[s] + N_EXPERTS - 1) % N_EXPERTS;   // (t-1) floor-mod 48
    const int rank = atomicAdd(&cnt[e], 1);
    __syncthreads();
    if (s == 0) {
        int acc = 0;
        for (int i = 0; i < N_EXPERTS; ++i) { off[i] = acc; acc += cnt[i]; }
        off[N_EXPERTS] = acc;             // = 512
    }
    __syncthreads();
    ws[off[e] + rank] = s;
    if (s <= N_EXPERTS) ws[BATCH + s] = off[s];
}

// Write bias[(t-1) mod 48] into out — out is poisoned 0xAA before every call,
// so this must be a plain store (the dot kernel then atomicAdds partials).
__global__ void init_out_kernel(const int* __restrict__ t,
                                const float* __restrict__ b,
                                float* __restrict__ out) {
    int i = blockIdx.x * blockDim.x + threadIdx.x;   // over BATCH*D_OUT
    if (i < BATCH * D_OUT) {
        int s = i >> 1;
        int k = i & 1;
        int e = (t[s] + N_EXPERTS - 1) % N_EXPERTS;
        out[i] = b[e * D_OUT + k];
    }
}

// ---------------------------------------------------------------------------
// Pass 1: persistent per-(chunk, expert) blocks, W cached in REGISTERS.
// Each block loads its 4096-elem W slice once (8 float4/thread), then loops
// over the expert's samples streaming x. W HBM traffic = 62.9 MB exactly;
// x = 335 MB exactly. No LDS in the hot path → no bank conflicts.
// ---------------------------------------------------------------------------
__global__ __launch_bounds__(THREADS) void moe_dot_kernel(
        const float* __restrict__ x,
        const int* __restrict__ ws,
        const float* __restrict__ W,
        float* __restrict__ out) {
    const int chunk = blockIdx.x;        // 0..NCHUNK-1
    const int e     = blockIdx.y;        // 0..N_EXPERTS-1
    const int start = ws[BATCH + e];
    const int end   = ws[BATCH + e + 1];
    if (start == end) return;            // expert got no samples

    const int tid = threadIdx.x;

    // W slab [D_IN][2] interleaved: x-float4 index i (elems 4i..4i+3) pairs
    // with W float4s 2i, 2i+1 (floats 8i..8i+7). Load this block's 8/thread.
    const float4* __restrict__ wq =
        (const float4*)(W + (size_t)e * D_IN * D_OUT + (size_t)chunk * CHUNK_E * D_OUT);
    float4 w[2 * F4T];
#pragma unroll
    for (int j = 0; j < F4T; ++j) {
        const int i = tid + THREADS * j;
        w[2 * j]     = wq[2 * i];       // (W[4i][0],W[4i][1],W[4i+1][0],W[4i+1][1])
        w[2 * j + 1] = wq[2 * i + 1];   // (W[4i+2][0],W[4i+2][1],W[4i+3][0],W[4i+3][1])
    }

    const int lane = tid & 63;

    for (int slot = start; slot < end; ++slot) {
        const int sample = ws[slot];
        const nfloat4* __restrict__ xp =
            (const nfloat4*)(x + (size_t)sample * D_IN + (size_t)chunk * CHUNK_E);

        float acc0 = 0.f, acc1 = 0.f;
#pragma unroll
        for (int j = 0; j < F4T; ++j) {
            nfloat4 xv = __builtin_nontemporal_load(&xp[tid + THREADS * j]);
            float4 w0 = w[2 * j];
            float4 w1 = w[2 * j + 1];
            acc0 += xv.x * w0.x + xv.y * w0.z + xv.z * w1.x + xv.w * w1.z;
            acc1 += xv.x * w0.y + xv.y * w0.w + xv.z * w1.y + xv.w * w1.w;
        }

        // wave-level butterfly; one atomic pair per wave (4 waves/block)
        for (int off = 32; off > 0; off >>= 1) {
            acc0 += __shfl_down(acc0, off);
            acc1 += __shfl_down(acc1, off);
        }
        if (lane == 0) {
            atomicAdd(&out[sample * D_OUT + 0], acc0);
            atomicAdd(&out[sample * D_OUT + 1], acc1);
        }
    }
}

extern "C" void kernel_launch(void* const* d_in, const int* in_sizes, int n_in,
                              void* d_out, int out_size, void* d_ws, size_t ws_size,
                              hipStream_t stream) {
    const float* x = (const float*)d_in[0];   // [512, 163840]
    const int*   t = (const int*)d_in[1];     // [512]
    const float* W = (const float*)d_in[2];   // [48, 163840, 2]
    const float* b = (const float*)d_in[3];   // [48, 2]
    float* out = (float*)d_out;               // [512, 2]
    int* ws = (int*)d_ws;

    // 0) expert-sort the samples + segment offsets (one tiny block)
    bucket_kernel<<<1, BATCH, 0, stream>>>(t, ws);

    // 1) out = bias[(t-1)%48]
    init_out_kernel<<<(BATCH * D_OUT + THREADS - 1) / THREADS, THREADS, 0, stream>>>(
        t, b, out);

    // 2) out += partial dots; W register-resident, read once by construction
    dim3 grid(NCHUNK, N_EXPERTS);
    moe_dot_kernel<<<grid, THREADS, 0, stream>>>(x, ws, W, out);
}